// Round 5
// baseline (1244.324 us; speedup 1.0000x reference)
//
#include <hip/hip_runtime.h>

#define B_ 8
#define C_ 64
#define T_ 256
#define F_ 256
#define H_ 128
#define TF_ (T_*F_)

typedef _Float16 half_t;
typedef _Float16 half8 __attribute__((ext_vector_type(8)));
typedef float float4v __attribute__((ext_vector_type(4)));

#if __has_builtin(__builtin_amdgcn_exp2f)
#define EXP2F(x) __builtin_amdgcn_exp2f(x)
#else
static __device__ inline float EXP2F(float x) { float r; asm("v_exp_f32 %0, %1" : "=v"(r) : "v"(x)); return r; }
#endif
#if __has_builtin(__builtin_amdgcn_rcpf)
#define RCPF(x) __builtin_amdgcn_rcpf(x)
#else
static __device__ inline float RCPF(float x) { float r; asm("v_rcp_f32 %0, %1" : "=v"(r) : "v"(x)); return r; }
#endif

#define NEG_L2E  (-1.4426950408889634f)
#define NEG_2L2E (-2.8853900817779268f)

// ---------------- Kernel 1: fused dual GRU, MFMA 16x16x32 f16, M=16/block ----------------
// R5: k_transpose ELIMINATED. x [B,C,T,F] fp32 is gathered directly into MFMA
// A-fragments with per-lane global_load_dword (uniform SGPR base stepped by
// scalar adds; loop-invariant per-lane offsets). t-GRU: each load fully uses
// 4x 64B lines (16 consecutive f per quad) - zero overfetch. f-GRU: lines are
// reused over 16 consecutive steps from an ~8KB L1-resident working set.
// This removes the transpose kernel (~40us incl launch) and 128MB of HBM
// round-trip for +16 loads +16 cvt per wave/step inside k_gru.
// Epilogue stays fused (5 trans/rg): h = [h_old(1+En)+Ez(1-En)]/[(1+En)(1+Ez)].
// No SGB (R4: -10%, dependent-VALU-after-MFMA bubble), no setprio (R2: -7%).
__device__ inline half8 load_w8s(const float* __restrict__ p, float s) {
    half8 r;
#pragma unroll
    for (int k = 0; k < 8; ++k) r[k] = (half_t)(p[k] * s);
    return r;
}

#define MFMA(a, b, c) __builtin_amdgcn_mfma_f32_16x16x32_f16((a), (b), (c), 0, 0, 0)

// A-frag: lane holds A[m=lane&15][k=quad*8+j]; B-frag: B[k=quad*8+j][n=lane&15];
// C/D: lane holds D[m=quad*4+reg][n=lane&15].
__global__ __launch_bounds__(512, 2) void k_gru(
    const float* __restrict__ x,
    const float* __restrict__ Wih_t, const float* __restrict__ Whh_t,
    const float* __restrict__ bih_t, const float* __restrict__ bhh_t,
    const float* __restrict__ Wih_f, const float* __restrict__ Whh_f,
    const float* __restrict__ bih_f, const float* __restrict__ bhh_f,
    float* __restrict__ h_t_out, float* __restrict__ h_f_out) {
    __shared__ half_t hbuf0[16 * 136];
    __shared__ half_t hbuf1[16 * 136];

    int tid  = threadIdx.x;
    int w    = tid >> 6;
    int lane = tid & 63;
    int nidx = lane & 15;
    int quad = lane >> 4;

    int bi  = blockIdx.x;
    bool isf = bi >= 128;
    int lbi = bi & 127;
    int b   = lbi >> 4;
    int g16 = (lbi & 15) << 4;    // f0 (time) or t0 (freq)

    const float* Wih = isf ? Wih_f : Wih_t;
    const float* Whh = isf ? Whh_f : Whh_t;
    const float* bih = isf ? bih_f : bih_t;
    const float* bhh = isf ? bhh_f : bhh_t;
    float* hout      = isf ? h_f_out : h_t_out;

    // ---- direct-x gather addressing ----
    // x elem (b,c,t,f) at ((b*64+c)*256 + t)*256 + f.
    // t-GRU: seq = f = g16+nidx, step = t: lane stride Lm=1, step advance As=256.
    // f-GRU: seq = t = g16+nidx, step = f: lane stride Lm=256, step advance As=1.
    int Lm = isf ? 256 : 1;
    int As = isf ? 1 : 256;
    const float* bp1 = x + (size_t)b * (64 * 65536) + (size_t)g16 * Lm;  // c in [0,32)
    const float* bp2 = bp1 + 32 * 65536;                                  // c in [32,64)
    int xoff = quad * 8 * 65536 + nidx * Lm;   // per-lane, loop-invariant

    // issue 16 scalar loads for one step's A-frags (fp32), advance bases (scalar)
#define XLOAD(dst)                                                              \
    {                                                                           \
        _Pragma("unroll")                                                       \
        for (int j = 0; j < 8; ++j) {                                           \
            (dst)[j]     = bp1[xoff + j * 65536];                               \
            (dst)[8 + j] = bp2[xoff + j * 65536];                               \
        }                                                                       \
        bp1 += As; bp2 += As;                                                   \
    }

    // ---- weight B-fragments in registers (loaded once, pre-scaled) ----
    int gr = w * 16 + nidx;     // r gate row  [0,128)
    int gz = gr + 128;          // z gate row
    int gn = gr + 256;          // n gate row
    int ko = quad * 8;

    half8 wir0 = load_w8s(Wih + gr * 64 + ko,      NEG_L2E);
    half8 wir1 = load_w8s(Wih + gr * 64 + 32 + ko, NEG_L2E);
    half8 wiz0 = load_w8s(Wih + gz * 64 + ko,      NEG_L2E);
    half8 wiz1 = load_w8s(Wih + gz * 64 + 32 + ko, NEG_L2E);
    half8 win0 = load_w8s(Wih + gn * 64 + ko,      NEG_2L2E);
    half8 win1 = load_w8s(Wih + gn * 64 + 32 + ko, NEG_2L2E);
    half8 whr[4], whz[4], whn[4];
#pragma unroll
    for (int kt = 0; kt < 4; ++kt) {
        whr[kt] = load_w8s(Whh + gr * 128 + kt * 32 + ko, NEG_L2E);
        whz[kt] = load_w8s(Whh + gz * 128 + kt * 32 + ko, NEG_L2E);
        whn[kt] = load_w8s(Whh + gn * 128 + kt * 32 + ko, NEG_2L2E);
    }
    float br  = NEG_L2E  * (bih[gr] + bhh[gr]);
    float bz  = NEG_L2E  * (bih[gz] + bhh[gz]);
    float bin = NEG_2L2E * bih[gn];
    float bhn = NEG_2L2E * bhh[gn];
    // persistent bias vectors: used directly as MFMA C operands (D != C is legal)
    float4v brv  = {br, br, br, br};
    float4v bzv  = {bz, bz, bz, bz};
    float4v bnv  = {bin, bin, bin, bin};
    float4v bhnv = {bhn, bhn, bhn, bhn};

    for (int idx = tid; idx < 16 * 136; idx += 512) hbuf0[idx] = (half_t)0.f;
    float h_old[4] = {0.f, 0.f, 0.f, 0.f};

    float xrawA[16], xrawB[16];
    XLOAD(xrawA);    // x_0
    XLOAD(xrawB);    // x_1  (bases now point at x_2)

    // x-part accumulators for step 0 (from x_0), seeded from bias vectors
    half8 a0, a1;
#pragma unroll
    for (int k2 = 0; k2 < 8; ++k2) { a0[k2] = (half_t)xrawA[k2]; a1[k2] = (half_t)xrawA[8 + k2]; }
    float4v xrE = MFMA(a0, wir0, brv); xrE = MFMA(a1, wir1, xrE);
    float4v xzE = MFMA(a0, wiz0, bzv); xzE = MFMA(a1, wiz1, xzE);
    float4v xnE = MFMA(a0, win0, bnv); xnE = MFMA(a1, win1, xnE);
    float4v xrO = {0.f, 0.f, 0.f, 0.f};
    float4v xzO = {0.f, 0.f, 0.f, 0.f};
    float4v xnO = {0.f, 0.f, 0.f, 0.f};
    __syncthreads();

    // XR/XZ/XN: this step's accumulators (x-part already in; h-part chains on top).
    // XRn/XZn/XNn: refilled for the NEXT step from XCraw (fp32, loaded 1 step ago).
    // XPraw: prefetch dest for t+2. PRE/REF literal flags gate tail steps (OOB safety).
#define GRU_STEP(RBUF, WBUF, XR, XZ, XN, XRn, XZn, XNn, XCraw, XPraw, PRE, REF) \
    {                                                                           \
        const half_t* hrow = (RBUF) + nidx * 136 + ko;                          \
        half8 ha0 = *(const half8*)(hrow);                                      \
        half8 ha1 = *(const half8*)(hrow + 32);                                 \
        half8 ha2 = *(const half8*)(hrow + 64);                                 \
        half8 ha3 = *(const half8*)(hrow + 96);                                 \
        if (PRE) { XLOAD(XPraw); }                                              \
        XR = MFMA(ha0, whr[0], XR); XR = MFMA(ha1, whr[1], XR);                 \
        XR = MFMA(ha2, whr[2], XR); XR = MFMA(ha3, whr[3], XR);                 \
        XZ = MFMA(ha0, whz[0], XZ); XZ = MFMA(ha1, whz[1], XZ);                 \
        XZ = MFMA(ha2, whz[2], XZ); XZ = MFMA(ha3, whz[3], XZ);                 \
        float4v hnv = MFMA(ha0, whn[0], bhnv);                                  \
        hnv = MFMA(ha1, whn[1], hnv);                                           \
        float rr[4], Ez[4];                                                     \
        _Pragma("unroll")                                                       \
        for (int rg = 0; rg < 4; ++rg) rr[rg] = RCPF(1.f + EXP2F(XR[rg]));      \
        hnv = MFMA(ha2, whn[2], hnv);                                           \
        hnv = MFMA(ha3, whn[3], hnv);                                           \
        _Pragma("unroll")                                                       \
        for (int rg = 0; rg < 4; ++rg) Ez[rg] = EXP2F(XZ[rg]);                  \
        if (REF) {                                                              \
            half8 c0, c1;                                                       \
            _Pragma("unroll")                                                   \
            for (int k2 = 0; k2 < 8; ++k2) {                                    \
                c0[k2] = (half_t)(XCraw)[k2];                                   \
                c1[k2] = (half_t)(XCraw)[8 + k2];                               \
            }                                                                   \
            XRn = MFMA(c0, wir0, brv); XRn = MFMA(c1, wir1, XRn);               \
            XZn = MFMA(c0, wiz0, bzv); XZn = MFMA(c1, wiz1, XZn);               \
            XNn = MFMA(c0, win0, bnv); XNn = MFMA(c1, win1, XNn);               \
        }                                                                       \
        _Pragma("unroll")                                                       \
        for (int rg = 0; rg < 4; ++rg) {                                        \
            float np  = XN[rg] + rr[rg] * hnv[rg];                              \
            float En  = EXP2F(np);                                              \
            float u   = __builtin_fmaf(h_old[rg], En, h_old[rg]);               \
            float t2  = u + Ez[rg];                                             \
            float num = __builtin_fmaf(-En, Ez[rg], t2);                        \
            float den = (1.f + En) * (1.f + Ez[rg]);                            \
            float h   = num * RCPF(den);                                        \
            h_old[rg] = h;                                                      \
            (WBUF)[(quad * 4 + rg) * 136 + w * 16 + nidx] = (half_t)h;          \
        }                                                                       \
        __syncthreads();                                                        \
    }

    for (int it = 0; it < 127; ++it) {
        // step t=2it: reads hbuf0, writes hbuf1; refill O from xrawB (x_{t+1}); prefetch x_{t+2} into xrawA
        GRU_STEP(hbuf0, hbuf1, xrE, xzE, xnE, xrO, xzO, xnO, xrawB, xrawA, 1, 1)
        // step t=2it+1: reads hbuf1, writes hbuf0; refill E from xrawA; prefetch into xrawB
        GRU_STEP(hbuf1, hbuf0, xrO, xzO, xnO, xrE, xzE, xnE, xrawA, xrawB, 1, 1)
    }
    // step 254: refill O from xrawB (= x_255, loaded at step 253); no prefetch (OOB)
    GRU_STEP(hbuf0, hbuf1, xrE, xzE, xnE, xrO, xzO, xnO, xrawB, xrawA, 0, 1)
    // step 255: final; no refill, no prefetch
    GRU_STEP(hbuf1, hbuf0, xrO, xzO, xnO, xrE, xzE, xnE, xrawA, xrawB, 0, 0)
#undef GRU_STEP
#undef XLOAD

    int srow = (b << 8) + g16;
#pragma unroll
    for (int rg = 0; rg < 4; ++rg) {
        hout[(size_t)(srow + quad * 4 + rg) * H_ + w * 16 + nidx] = h_old[rg];
    }
}

// ---------------- Kernel 2: out[b,c,t,f] = bp[c] + sum_h Wp[c,h]*(h_t[b,t,h]+h_f[b,t,h]) ----------------
__global__ __launch_bounds__(256) void k_out(const float* __restrict__ h_t,
                                             const float* __restrict__ h_f,
                                             const float* __restrict__ Wp,
                                             const float* __restrict__ bp,
                                             float* __restrict__ out) {
    __shared__ float sv[128];
    __shared__ float part[4][64];
    __shared__ float orow[64];
    int blk = blockIdx.x;
    int b = blk >> 8;
    int i = blk & 255;              // t index
    int tid = threadIdx.x;
    size_t hoff = ((size_t)(b * 256 + i)) * 128;
    if (tid < 128) sv[tid] = h_t[hoff + tid] + h_f[hoff + tid];
    __syncthreads();
    int c = tid & 63;
    int q = tid >> 6;
    float p = 0.f;
    const float* wp = Wp + c * 128 + q * 32;
#pragma unroll
    for (int k = 0; k < 32; ++k) p += wp[k] * sv[q * 32 + k];
    part[q][c] = p;
    __syncthreads();
    if (tid < 64) orow[tid] = part[0][tid] + part[1][tid] + part[2][tid] + part[3][tid] + bp[tid];
    __syncthreads();
    // wave wv writes full contiguous rows out[b, c, i, 0:256] (1 KB each), non-temporal
    int wv   = tid >> 6;
    int lane = tid & 63;
#pragma unroll
    for (int itr = 0; itr < 16; ++itr) {
        int cc = itr * 4 + wv;
        float v = orow[cc];
        float4v vv = {v, v, v, v};
        __builtin_nontemporal_store(vv, (float4v*)(out + (((size_t)(b * 64 + cc)) * 256 + i) * 256 + lane * 4));
    }
}

extern "C" void kernel_launch(void* const* d_in, const int* in_sizes, int n_in,
                              void* d_out, int out_size, void* d_ws, size_t ws_size,
                              hipStream_t stream) {
    const float* x     = (const float*)d_in[0];
    const float* Wih_t = (const float*)d_in[1];
    const float* Whh_t = (const float*)d_in[2];
    const float* bih_t = (const float*)d_in[3];
    const float* bhh_t = (const float*)d_in[4];
    const float* Wih_f = (const float*)d_in[5];
    const float* Whh_f = (const float*)d_in[6];
    const float* bih_f = (const float*)d_in[7];
    const float* bhh_f = (const float*)d_in[8];
    const float* Wp    = (const float*)d_in[9];
    const float* bp    = (const float*)d_in[10];
    float* out = (float*)d_out;

    // h_t/h_f live in ws; x is read directly by k_gru (no transpose pass).
    float* h_t_out = (float*)((char*)d_ws);
    float* h_f_out = (float*)((char*)d_ws + (size_t)2048 * 128 * 4);

    k_gru<<<256, 512, 0, stream>>>(x, Wih_t, Whh_t, bih_t, bhh_t,
                                   Wih_f, Whh_f, bih_f, bhh_f, h_t_out, h_f_out);
    k_out<<<2048, 256, 0, stream>>>(h_t_out, h_f_out, Wp, bp, out);
}

// Round 6
// 387.748 us; speedup vs baseline: 3.2091x; 3.2091x over previous
//
#include <hip/hip_runtime.h>

#define B_ 8
#define C_ 64
#define T_ 256
#define F_ 256
#define H_ 128
#define TF_ (T_*F_)

typedef _Float16 half_t;
typedef _Float16 half8 __attribute__((ext_vector_type(8)));
typedef float float4v __attribute__((ext_vector_type(4)));

#if __has_builtin(__builtin_amdgcn_exp2f)
#define EXP2F(x) __builtin_amdgcn_exp2f(x)
#else
static __device__ inline float EXP2F(float x) { float r; asm("v_exp_f32 %0, %1" : "=v"(r) : "v"(x)); return r; }
#endif
#if __has_builtin(__builtin_amdgcn_rcpf)
#define RCPF(x) __builtin_amdgcn_rcpf(x)
#else
static __device__ inline float RCPF(float x) { float r; asm("v_rcp_f32 %0, %1" : "=v"(r) : "v"(x)); return r; }
#endif

#define NEG_L2E  (-1.4426950408889634f)
#define NEG_2L2E (-2.8853900817779268f)

// x-tile LDS layout: [s=8][m=16][c=64] fp16. m-stride 72 elems (144B, 16B-aligned
// rows for ds_read_b128); s-stride 1160 elems (16*72 + 8 pad: breaks the
// write-phase bank alignment from 32-way down to ~8-way on 2 instr/step).
#define XS_M 72
#define XS_S 1160

// ---------------- Kernel 1: fused dual GRU, MFMA 16x16x32 f16, M=16/block ----------------
// R6: k_transpose folded into k_gru via double-buffered 8-step LDS x-tiles.
// Tile = x[b, all c, 8 steps x 16 seqs] (32KB fp32 -> 16KB fp16 in LDS).
// Global loads are float4 along f (fully-used 64B lines; 4 loads/thread/tile
// = 0.5/step); transpose happens on the fp16 ds_writes at tile boundaries
// (16 b16-writes/thread/tile, amortized 2/step). Per-step x A-frags come from
// LDS (2x conflict-free ds_read_b128). Staging loads have 8 steps (~6us) of
// slack -> latency fully hidden (fixes R5's per-lane-gather MSHR collapse,
// which was MfmaUtil 5.6% / 1138us).
// Epilogue stays fused (5 trans/rg): h = [h_old(1+En)+Ez(1-En)]/[(1+En)(1+Ez)].
// No SGB (R4: -10%), no setprio (R2: -7%).
__device__ inline half8 load_w8s(const float* __restrict__ p, float s) {
    half8 r;
#pragma unroll
    for (int k = 0; k < 8; ++k) r[k] = (half_t)(p[k] * s);
    return r;
}

#define MFMA(a, b, c) __builtin_amdgcn_mfma_f32_16x16x32_f16((a), (b), (c), 0, 0, 0)

// A-frag: lane holds A[m=lane&15][k=quad*8+j]; B-frag: B[k=quad*8+j][n=lane&15];
// C/D: lane holds D[m=quad*4+reg][n=lane&15].
__global__ __launch_bounds__(512, 2) void k_gru(
    const float* __restrict__ x,
    const float* __restrict__ Wih_t, const float* __restrict__ Whh_t,
    const float* __restrict__ bih_t, const float* __restrict__ bhh_t,
    const float* __restrict__ Wih_f, const float* __restrict__ Whh_f,
    const float* __restrict__ bih_f, const float* __restrict__ bhh_f,
    float* __restrict__ h_t_out, float* __restrict__ h_f_out) {
    __shared__ half_t hbuf0[16 * 136];
    __shared__ half_t hbuf1[16 * 136];
    __shared__ half_t xt0[8 * XS_S];
    __shared__ half_t xt1[8 * XS_S];

    int tid  = threadIdx.x;
    int w    = tid >> 6;
    int lane = tid & 63;
    int nidx = lane & 15;
    int quad = lane >> 4;

    int bi  = blockIdx.x;
    bool isf = bi >= 128;
    int lbi = bi & 127;
    int b   = lbi >> 4;
    int g16 = (lbi & 15) << 4;    // f0 (time) or t0 (freq)

    const float* Wih = isf ? Wih_f : Wih_t;
    const float* Whh = isf ? Whh_f : Whh_t;
    const float* bih = isf ? bih_f : bih_t;
    const float* bhh = isf ? bhh_f : bhh_t;
    float* hout      = isf ? h_f_out : h_t_out;

    // ---- staging addressing ----
    // tile tIdx: t-GRU covers t in [8tIdx, 8tIdx+8), f in [g16, g16+16)
    //            f-GRU covers f in [8tIdx, 8tIdx+8), t in [g16, g16+16)
    // thread reads 4x float4 along f; each float4 = 4 consecutive f.
    // t-GRU: f is the m-axis (float4 spans 4 m at one s=t-local)
    // f-GRU: f is the s-axis (float4 spans 4 s at one m=t-local)
    int fq, rowid;
    if (!isf) { fq = tid & 3; rowid = tid >> 2; }
    else      { fq = tid & 1; rowid = tid >> 1; }
    int goff[4], ldsoff[4];
#pragma unroll
    for (int j = 0; j < 4; ++j) {
        int row = rowid + (isf ? 256 : 128) * j;
        int c   = isf ? (row >> 4) : (row >> 3);
        int tl  = isf ? (row & 15) : (row & 7);
        goff[j]   = c * 65536 + tl * 256 + 4 * fq;
        ldsoff[j] = isf ? ((4 * fq) * XS_S + tl * XS_M + c)
                        : (tl * XS_S + (4 * fq) * XS_M + c);
    }
    int estr = isf ? XS_S : XS_M;      // stride between the 4 elems of a float4
    int As8  = isf ? 8 : 8 * 256;      // tile-to-tile advance (floats)
    const float* gb = x + (size_t)b * (64 * 65536) + (size_t)(isf ? g16 * 256 : g16);

#define XLOADG()                                                                \
    {                                                                           \
        _Pragma("unroll")                                                       \
        for (int j = 0; j < 4; ++j) rS[j] = *(const float4v*)(gb + goff[j]);    \
        gb += As8;                                                              \
    }
#define XWRITE(XT)                                                              \
    {                                                                           \
        _Pragma("unroll")                                                       \
        for (int j = 0; j < 4; ++j) {                                           \
            _Pragma("unroll")                                                   \
            for (int e = 0; e < 4; ++e)                                         \
                (XT)[ldsoff[j] + e * estr] = (half_t)rS[j][e];                  \
        }                                                                       \
    }

    // ---- weight B-fragments in registers (loaded once, pre-scaled) ----
    int gr = w * 16 + nidx;     // r gate row  [0,128)
    int gz = gr + 128;          // z gate row
    int gn = gr + 256;          // n gate row
    int ko = quad * 8;

    half8 wir0 = load_w8s(Wih + gr * 64 + ko,      NEG_L2E);
    half8 wir1 = load_w8s(Wih + gr * 64 + 32 + ko, NEG_L2E);
    half8 wiz0 = load_w8s(Wih + gz * 64 + ko,      NEG_L2E);
    half8 wiz1 = load_w8s(Wih + gz * 64 + 32 + ko, NEG_L2E);
    half8 win0 = load_w8s(Wih + gn * 64 + ko,      NEG_2L2E);
    half8 win1 = load_w8s(Wih + gn * 64 + 32 + ko, NEG_2L2E);
    half8 whr[4], whz[4], whn[4];
#pragma unroll
    for (int kt = 0; kt < 4; ++kt) {
        whr[kt] = load_w8s(Whh + gr * 128 + kt * 32 + ko, NEG_L2E);
        whz[kt] = load_w8s(Whh + gz * 128 + kt * 32 + ko, NEG_L2E);
        whn[kt] = load_w8s(Whh + gn * 128 + kt * 32 + ko, NEG_2L2E);
    }
    float br  = NEG_L2E  * (bih[gr] + bhh[gr]);
    float bz  = NEG_L2E  * (bih[gz] + bhh[gz]);
    float bin = NEG_2L2E * bih[gn];
    float bhn = NEG_2L2E * bhh[gn];
    float4v brv  = {br, br, br, br};
    float4v bzv  = {bz, bz, bz, bz};
    float4v bnv  = {bin, bin, bin, bin};
    float4v bhnv = {bhn, bhn, bhn, bhn};

    for (int idx = tid; idx < 16 * 136; idx += 512) hbuf0[idx] = (half_t)0.f;
    float h_old[4] = {0.f, 0.f, 0.f, 0.f};

    // prologue: xt0 <- tile0, xt1 <- tile1, rS <- tile2
    float4v rS[4];
    XLOADG(); XWRITE(xt0);
    XLOADG(); XWRITE(xt1);
    XLOADG();
    __syncthreads();

    // seed x-part accumulators for step 0 from x_0 (xt0, row 0)
    float4v xrE, xzE, xnE;
    {
        const half_t* xrp = xt0 + nidx * XS_M + ko;
        half8 a0 = *(const half8*)xrp;
        half8 a1 = *(const half8*)(xrp + 32);
        xrE = MFMA(a0, wir0, brv); xrE = MFMA(a1, wir1, xrE);
        xzE = MFMA(a0, wiz0, bzv); xzE = MFMA(a1, wiz1, xzE);
        xnE = MFMA(a0, win0, bnv); xnE = MFMA(a1, win1, xnE);
    }
    float4v xrO = {0.f, 0.f, 0.f, 0.f};
    float4v xzO = {0.f, 0.f, 0.f, 0.f};
    float4v xnO = {0.f, 0.f, 0.f, 0.f};

    // Step t (= 16*tt + k) reads h from RBUF, writes WBUF; refills next step's
    // xacc from x_{t+1} = tile ((t+1)>>3) row ((t+1)&7), read from LDS (XTB/SROW).
    // STG runs at tile boundaries: write staged tile regs -> LDS, load next tile.
#define GRU_STEP(RBUF, WBUF, XR, XZ, XN, XRn, XZn, XNn, XTB, SROW, REF, STG)    \
    {                                                                           \
        const half_t* hrow = (RBUF) + nidx * 136 + ko;                          \
        half8 ha0 = *(const half8*)(hrow);                                      \
        half8 ha1 = *(const half8*)(hrow + 32);                                 \
        half8 ha2 = *(const half8*)(hrow + 64);                                 \
        half8 ha3 = *(const half8*)(hrow + 96);                                 \
        half8 c0x, c1x;                                                         \
        if (REF) {                                                              \
            const half_t* xrp = (XTB) + (SROW) * XS_S + nidx * XS_M + ko;       \
            c0x = *(const half8*)xrp;                                           \
            c1x = *(const half8*)(xrp + 32);                                    \
        }                                                                       \
        XR = MFMA(ha0, whr[0], XR); XR = MFMA(ha1, whr[1], XR);                 \
        XR = MFMA(ha2, whr[2], XR); XR = MFMA(ha3, whr[3], XR);                 \
        XZ = MFMA(ha0, whz[0], XZ); XZ = MFMA(ha1, whz[1], XZ);                 \
        XZ = MFMA(ha2, whz[2], XZ); XZ = MFMA(ha3, whz[3], XZ);                 \
        float4v hnv = MFMA(ha0, whn[0], bhnv);                                  \
        hnv = MFMA(ha1, whn[1], hnv);                                           \
        float rr[4], Ez[4];                                                     \
        _Pragma("unroll")                                                       \
        for (int rg = 0; rg < 4; ++rg) rr[rg] = RCPF(1.f + EXP2F(XR[rg]));      \
        hnv = MFMA(ha2, whn[2], hnv);                                           \
        hnv = MFMA(ha3, whn[3], hnv);                                           \
        _Pragma("unroll")                                                       \
        for (int rg = 0; rg < 4; ++rg) Ez[rg] = EXP2F(XZ[rg]);                  \
        if (REF) {                                                              \
            XRn = MFMA(c0x, wir0, brv); XRn = MFMA(c1x, wir1, XRn);             \
            XZn = MFMA(c0x, wiz0, bzv); XZn = MFMA(c1x, wiz1, XZn);             \
            XNn = MFMA(c0x, win0, bnv); XNn = MFMA(c1x, win1, XNn);             \
        }                                                                       \
        STG                                                                     \
        _Pragma("unroll")                                                       \
        for (int rg = 0; rg < 4; ++rg) {                                        \
            float np  = XN[rg] + rr[rg] * hnv[rg];                              \
            float En  = EXP2F(np);                                              \
            float u   = __builtin_fmaf(h_old[rg], En, h_old[rg]);               \
            float t2  = u + Ez[rg];                                             \
            float num = __builtin_fmaf(-En, Ez[rg], t2);                        \
            float den = (1.f + En) * (1.f + Ez[rg]);                            \
            float h   = num * RCPF(den);                                        \
            h_old[rg] = h;                                                      \
            (WBUF)[(quad * 4 + rg) * 136 + w * 16 + nidx] = (half_t)h;          \
        }                                                                       \
        __syncthreads();                                                        \
    }

    for (int tt = 0; tt < 16; ++tt) {
        // k=0..6: read x rows 1..7 of xt0 (tile 2tt)
        GRU_STEP(hbuf0, hbuf1, xrE, xzE, xnE, xrO, xzO, xnO, xt0, 1, 1, {})
        GRU_STEP(hbuf1, hbuf0, xrO, xzO, xnO, xrE, xzE, xnE, xt0, 2, 1, {})
        GRU_STEP(hbuf0, hbuf1, xrE, xzE, xnE, xrO, xzO, xnO, xt0, 3, 1, {})
        GRU_STEP(hbuf1, hbuf0, xrO, xzO, xnO, xrE, xzE, xnE, xt0, 4, 1, {})
        GRU_STEP(hbuf0, hbuf1, xrE, xzE, xnE, xrO, xzO, xnO, xt0, 5, 1, {})
        GRU_STEP(hbuf1, hbuf0, xrO, xzO, xnO, xrE, xzE, xnE, xt0, 6, 1, {})
        GRU_STEP(hbuf0, hbuf1, xrE, xzE, xnE, xrO, xzO, xnO, xt0, 7, 1, {})
        // k=7: reads xt1 row 0 (tile 2tt+1); stage tile 2tt+2 -> xt0 (last xt0
        // read was k=6, sealed by its barrier); load tile 2tt+3.
        GRU_STEP(hbuf1, hbuf0, xrO, xzO, xnO, xrE, xzE, xnE, xt1, 0, 1,
                 { if (tt < 15) { XWRITE(xt0); XLOADG(); } })
        // k=8..14: read x rows 1..7 of xt1 (tile 2tt+1)
        GRU_STEP(hbuf0, hbuf1, xrE, xzE, xnE, xrO, xzO, xnO, xt1, 1, 1, {})
        GRU_STEP(hbuf1, hbuf0, xrO, xzO, xnO, xrE, xzE, xnE, xt1, 2, 1, {})
        GRU_STEP(hbuf0, hbuf1, xrE, xzE, xnE, xrO, xzO, xnO, xt1, 3, 1, {})
        GRU_STEP(hbuf1, hbuf0, xrO, xzO, xnO, xrE, xzE, xnE, xt1, 4, 1, {})
        GRU_STEP(hbuf0, hbuf1, xrE, xzE, xnE, xrO, xzO, xnO, xt1, 5, 1, {})
        GRU_STEP(hbuf1, hbuf0, xrO, xzO, xnO, xrE, xzE, xnE, xt1, 6, 1, {})
        GRU_STEP(hbuf0, hbuf1, xrE, xzE, xnE, xrO, xzO, xnO, xt1, 7, 1, {})
        // k=15: reads xt0 row 0 (tile 2tt+2, written at k=7, barrier since);
        // stage tile 2tt+3 -> xt1; load tile 2tt+4. Final step (tt=15): no
        // refill, no staging.
        GRU_STEP(hbuf1, hbuf0, xrO, xzO, xnO, xrE, xzE, xnE, xt0, 0, (tt < 15),
                 { if (tt < 15) { XWRITE(xt1); if (tt < 14) { XLOADG(); } } })
    }
#undef GRU_STEP
#undef XWRITE
#undef XLOADG

    int srow = (b << 8) + g16;
#pragma unroll
    for (int rg = 0; rg < 4; ++rg) {
        hout[(size_t)(srow + quad * 4 + rg) * H_ + w * 16 + nidx] = h_old[rg];
    }
}

// ---------------- Kernel 2: out[b,c,t,f] = bp[c] + sum_h Wp[c,h]*(h_t[b,t,h]+h_f[b,t,h]) ----------------
__global__ __launch_bounds__(256) void k_out(const float* __restrict__ h_t,
                                             const float* __restrict__ h_f,
                                             const float* __restrict__ Wp,
                                             const float* __restrict__ bp,
                                             float* __restrict__ out) {
    __shared__ float sv[128];
    __shared__ float part[4][64];
    __shared__ float orow[64];
    int blk = blockIdx.x;
    int b = blk >> 8;
    int i = blk & 255;              // t index
    int tid = threadIdx.x;
    size_t hoff = ((size_t)(b * 256 + i)) * 128;
    if (tid < 128) sv[tid] = h_t[hoff + tid] + h_f[hoff + tid];
    __syncthreads();
    int c = tid & 63;
    int q = tid >> 6;
    float p = 0.f;
    const float* wp = Wp + c * 128 + q * 32;
#pragma unroll
    for (int k = 0; k < 32; ++k) p += wp[k] * sv[q * 32 + k];
    part[q][c] = p;
    __syncthreads();
    if (tid < 64) orow[tid] = part[0][tid] + part[1][tid] + part[2][tid] + part[3][tid] + bp[tid];
    __syncthreads();
    // wave wv writes full contiguous rows out[b, c, i, 0:256] (1 KB each), non-temporal
    int wv   = tid >> 6;
    int lane = tid & 63;
#pragma unroll
    for (int itr = 0; itr < 16; ++itr) {
        int cc = itr * 4 + wv;
        float v = orow[cc];
        float4v vv = {v, v, v, v};
        __builtin_nontemporal_store(vv, (float4v*)(out + (((size_t)(b * 64 + cc)) * 256 + i) * 256 + lane * 4));
    }
}

extern "C" void kernel_launch(void* const* d_in, const int* in_sizes, int n_in,
                              void* d_out, int out_size, void* d_ws, size_t ws_size,
                              hipStream_t stream) {
    const float* x     = (const float*)d_in[0];
    const float* Wih_t = (const float*)d_in[1];
    const float* Whh_t = (const float*)d_in[2];
    const float* bih_t = (const float*)d_in[3];
    const float* bhh_t = (const float*)d_in[4];
    const float* Wih_f = (const float*)d_in[5];
    const float* Whh_f = (const float*)d_in[6];
    const float* bih_f = (const float*)d_in[7];
    const float* bhh_f = (const float*)d_in[8];
    const float* Wp    = (const float*)d_in[9];
    const float* bp    = (const float*)d_in[10];
    float* out = (float*)d_out;

    // h_t/h_f live in ws; x is staged in-kernel (no transpose pass).
    float* h_t_out = (float*)((char*)d_ws);
    float* h_f_out = (float*)((char*)d_ws + (size_t)2048 * 128 * 4);

    k_gru<<<256, 512, 0, stream>>>(x, Wih_t, Whh_t, bih_t, bhh_t,
                                   Wih_f, Whh_f, bih_f, bhh_f, h_t_out, h_f_out);
    k_out<<<2048, 256, 0, stream>>>(h_t_out, h_f_out, Wp, bp, out);
}